// Round 2
// baseline (343.127 us; speedup 1.0000x reference)
//
#include <hip/hip_runtime.h>

// CascadedAttentionCell: B=64, T=512, D=1024, OUT=1024 (all fp32 in/out)
//   WaS = prev@Wa + Ba;  UaH = inputs@Ua (68.7 GFLOP, fp16 MFMA);
//   scores = relu(tanh(UaH+WaS+Ba)@Va); sm = softmax_T; out = sum_t inputs*sm
// R3 (retry — previous bench died to container infra failure, not the kernel):
// occupancy attack. fused_gemm was latency-bound (MfmaUtil 18.6%, HBM 12%,
// Occupancy 22% — 2 waves/SIMD, reg-capped by acc[2][4]=128 + grid=2 blocks/CU).
//   - wave tile 64x128 -> 64x64 (acc[2][2]=64 regs), 512-thread blocks (8 waves,
//     one 64-col group each), __launch_bounds__(512,4) => 4 waves/SIMD, 16/CU.
//   - traffic unchanged: A streamed 2x (pass2 hits L3), B read once per strip.
//   - k_ctx_part / k_was_part: 8 -> 16 slices (1024 blocks = 4/CU) for MLP.
//   - ctxPart (4 MB) overlays dead B16+wasPart; ws stays 6.5 MB.

#define NBATCH 64
#define NT     512
#define NDIM   1024
#define NOUT   1024

typedef _Float16 h8 __attribute__((ext_vector_type(8)));
typedef _Float16 h4 __attribute__((ext_vector_type(4)));
typedef float f16v __attribute__((ext_vector_type(16)));

__device__ __forceinline__ float tanh_fast(float x) {
    float e = __expf(2.0f * x);
    return 1.0f - 2.0f * __builtin_amdgcn_rcpf(e + 1.0f);
}

// ---- K2a: pack Ua (fp32 [K=1024][N=1024]) into fp16 B-fragment order ----
// t = ((nt*64+ks)*64) + kg*32 + nn ; thread writes 8 contiguous fp16 (16 B).
__global__ __launch_bounds__(256) void k_pack_ua(const float* __restrict__ Ua,
                                                 _Float16* __restrict__ B16) {
    int t = blockIdx.x * 256 + threadIdx.x;   // 0..131071
    int nn = t & 31, kg = (t >> 5) & 1, ks = (t >> 6) & 63, nt = t >> 12;
    int n = (nt << 5) + nn;
    int kbase = (ks << 4) + (kg << 3);
    h8 v;
#pragma unroll
    for (int j = 0; j < 8; ++j) v[j] = (_Float16)Ua[(size_t)(kbase + j) * 1024 + n];
    *(h8*)(B16 + ((size_t)t << 3)) = v;
}

// ---- K1: WaS partials: part[oc][b][p] = sum_{o in chunk} ps[b][o]*Wa[o][p] ----
// 16 chunks of 64 rows -> 1024 blocks (4/CU) for latency hiding.
__global__ __launch_bounds__(256) void k_was_part(const float* __restrict__ ps,
                                                  const float* __restrict__ Wa,
                                                  float* __restrict__ part) {
    int oc = blockIdx.x, b = blockIdx.y, tid = threadIdx.x;
    const float4* Wa4 = (const float4*)Wa;
    const float* psb = ps + b * 1024;
    float4 acc = {0.f, 0.f, 0.f, 0.f};
    int o0 = oc * 64;
#pragma unroll 4
    for (int o = o0; o < o0 + 64; ++o) {
        float s = psb[o];
        float4 wv = Wa4[o * 256 + tid];
        acc.x += s * wv.x; acc.y += s * wv.y; acc.z += s * wv.z; acc.w += s * wv.w;
    }
    ((float4*)part)[((oc << 6) + b) * 256 + tid] = acc;
}

// ---- K1b: wsWaS[b][p] = Ba[p] + sum_oc part ----
__global__ __launch_bounds__(256) void k_was_reduce(const float* __restrict__ part,
                                                    const float* __restrict__ Ba,
                                                    float* __restrict__ wsWaS) {
    int b = blockIdx.x, tid = threadIdx.x;
    const float4* p4 = (const float4*)part;
    float4 acc = ((const float4*)Ba)[tid];
#pragma unroll
    for (int oc = 0; oc < 16; ++oc) {
        float4 v = p4[((oc << 6) + b) * 256 + tid];
        acc.x += v.x; acc.y += v.y; acc.z += v.z; acc.w += v.w;
    }
    ((float4*)wsWaS)[b * 256 + tid] = acc;
}

// ---- K3: fused  scores[r] = relu( sum_n tanh(UaH[r][n]+wsWaS[b][n]) * Va[n] ) ----
// 512 threads = 8 waves; wave wv owns cols [pass*512 + wv*64, +64) (acc[2][2]).
// 64-row strip per block (grid 512); A chunk (64x128 fp32) double-buffered in LDS
// with register prefetch; B fragments streamed from L2-resident packed B16.
#define ASH_STRIDE 136   // fp16 units; 272 B rows: 16B-aligned, ~2 extra cyc/b128
__global__ __launch_bounds__(512, 4) void k_fused_gemm(
    const float* __restrict__ inputs, const _Float16* __restrict__ B16,
    const float* __restrict__ wsWaS, const float* __restrict__ Va,
    float* __restrict__ scores)
{
    __shared__ _Float16 Ash[2][64 * ASH_STRIDE];
    __shared__ float scoreSh[64];
    const int tid = threadIdx.x;                 // 0..511
    const int lane = tid & 63, wv = tid >> 6;    // wv = col group 0..7
    const int l31 = lane & 31, lhi = lane >> 5;
    const int r0 = blockIdx.x * 64;
    const int b = r0 >> 9;
    const int srow = tid >> 3, sq = tid & 7;     // 8 threads/row, 16 floats each
    const float4* srcBase = (const float4*)inputs + (size_t)(r0 + srow) * 256 + sq * 4;

    if (tid < 64) scoreSh[tid] = 0.0f;

    float4 vA[4];
#pragma unroll
    for (int j = 0; j < 4; ++j) vA[j] = srcBase[j];          // chunk 0
    {
        _Float16* dst = &Ash[0][srow * ASH_STRIDE + sq * 16];
#pragma unroll
        for (int j = 0; j < 4; ++j) {
            float4 v = vA[j];
            *(h4*)(dst + j * 4) =
                (h4){ (_Float16)v.x, (_Float16)v.y, (_Float16)v.z, (_Float16)v.w };
        }
    }
    __syncthreads();

    for (int pass = 0; pass < 2; ++pass) {
        const int c0w = pass * 512 + wv * 64;
        const int ntb = c0w >> 5;
        f16v acc[2][2];
#pragma unroll
        for (int rt = 0; rt < 2; ++rt)
#pragma unroll
            for (int ct = 0; ct < 2; ++ct)
#pragma unroll
                for (int e = 0; e < 16; ++e) acc[rt][ct][e] = 0.0f;

        for (int kc = 0; kc < 8; ++kc) {
            const int buf = kc & 1;
            const bool pf = !(pass == 1 && kc == 7);
            if (pf) {   // issue next chunk's HBM loads before the MFMAs
                const float4* src = srcBase + (((kc + 1) & 7) << 5);
#pragma unroll
                for (int j = 0; j < 4; ++j) vA[j] = src[j];
            }
#pragma unroll
            for (int ks8 = 0; ks8 < 8; ++ks8) {
                const int ks = kc * 8 + ks8;
                h8 a0 = *(const h8*)&Ash[buf][l31 * ASH_STRIDE + ks8 * 16 + lhi * 8];
                h8 a1 = *(const h8*)&Ash[buf][(32 + l31) * ASH_STRIDE + ks8 * 16 + lhi * 8];
                h8 bf[2];
#pragma unroll
                for (int ct = 0; ct < 2; ++ct)
                    bf[ct] = *(const h8*)(B16 +
                        ((size_t)(((ntb + ct) << 6) + ks) << 9) + lane * 8);
#pragma unroll
                for (int ct = 0; ct < 2; ++ct) {
                    acc[0][ct] = __builtin_amdgcn_mfma_f32_32x32x16_f16(a0, bf[ct], acc[0][ct], 0, 0, 0);
                    acc[1][ct] = __builtin_amdgcn_mfma_f32_32x32x16_f16(a1, bf[ct], acc[1][ct], 0, 0, 0);
                }
            }
            if (pf) {   // loads have drained during MFMAs; convert + stage
                _Float16* dst = &Ash[buf ^ 1][srow * ASH_STRIDE + sq * 16];
#pragma unroll
                for (int j = 0; j < 4; ++j) {
                    float4 v = vA[j];
                    *(h4*)(dst + j * 4) =
                        (h4){ (_Float16)v.x, (_Float16)v.y, (_Float16)v.z, (_Float16)v.w };
                }
            }
            __syncthreads();
        }
        // epilogue: tanh + Va dot, reduce over this wave's 64 cols
        float wsv[2], vav[2];
#pragma unroll
        for (int ct = 0; ct < 2; ++ct) {
            int n = c0w + ct * 32 + l31;
            wsv[ct] = wsWaS[b * 1024 + n];
            vav[ct] = Va[n];
        }
#pragma unroll
        for (int rt = 0; rt < 2; ++rt) {
#pragma unroll
            for (int i = 0; i < 16; ++i) {
                float s = 0.0f;
#pragma unroll
                for (int ct = 0; ct < 2; ++ct)
                    s += tanh_fast(acc[rt][ct][i] + wsv[ct]) * vav[ct];
                s += __shfl_xor(s, 1);
                s += __shfl_xor(s, 2);
                s += __shfl_xor(s, 4);
                s += __shfl_xor(s, 8);
                s += __shfl_xor(s, 16);
                if (l31 == 0) {
                    int row = rt * 32 + (i & 3) + ((i >> 2) << 3) + (lhi << 2);
                    atomicAdd(&scoreSh[row], s);
                }
            }
        }
    }
    __syncthreads();
    if (tid < 64) scores[r0 + tid] = fmaxf(scoreSh[tid], 0.0f);
}

// ---- K4: softmax over T=512 per batch ----
__global__ __launch_bounds__(256) void k_softmax(const float* __restrict__ scores,
                                                 float* __restrict__ sm) {
    int b = blockIdx.x, tid = threadIdx.x;
    __shared__ float red[256];
    const float* sb = scores + b * 512;
    float s0 = sb[tid], s1 = sb[tid + 256];
    red[tid] = fmaxf(s0, s1);
    __syncthreads();
    for (int st = 128; st > 0; st >>= 1) {
        if (tid < st) red[tid] = fmaxf(red[tid], red[tid + st]);
        __syncthreads();
    }
    float m = red[0];
    __syncthreads();
    float e0 = __expf(s0 - m), e1 = __expf(s1 - m);
    red[tid] = e0 + e1;
    __syncthreads();
    for (int st = 128; st > 0; st >>= 1) {
        if (tid < st) red[tid] += red[tid + st];
        __syncthreads();
    }
    float inv = 1.0f / red[0];
    sm[b * 512 + tid] = e0 * inv;
    sm[b * 512 + 256 + tid] = e1 * inv;
}

// ---- K5: context partials over 32-timestep slices (16 slices -> 1024 blocks) ----
__global__ __launch_bounds__(256) void k_ctx_part(const float* __restrict__ inputs,
                                                  const float* __restrict__ sm,
                                                  float* __restrict__ part) {
    int ts = blockIdx.x, b = blockIdx.y, tid = threadIdx.x;
    const float4* inF4 = (const float4*)inputs;
    float4 acc = {0.f, 0.f, 0.f, 0.f};
    int t0 = ts * 32;
#pragma unroll 8
    for (int t = t0; t < t0 + 32; ++t) {
        float wgt = sm[b * 512 + t];
        float4 x = inF4[(size_t)(b * 512 + t) * 256 + tid];
        acc.x += wgt * x.x; acc.y += wgt * x.y; acc.z += wgt * x.z; acc.w += wgt * x.w;
    }
    ((float4*)part)[((ts << 6) + b) * 256 + tid] = acc;
}

// ---- K6: reduce 16 slices -> d_out ----
__global__ __launch_bounds__(256) void k_ctx_reduce(const float* __restrict__ part,
                                                    float* __restrict__ out) {
    int g = blockIdx.x * 256 + threadIdx.x;
    const float4* p4 = (const float4*)part;
    float4 acc = p4[g];
#pragma unroll
    for (int s = 1; s < 16; ++s) {
        float4 v = p4[s * 16384 + g];
        acc.x += v.x; acc.y += v.y; acc.z += v.z; acc.w += v.w;
    }
    ((float4*)out)[g] = acc;
}

extern "C" void kernel_launch(void* const* d_in, const int* in_sizes, int n_in,
                              void* d_out, int out_size, void* d_ws, size_t ws_size,
                              hipStream_t stream) {
    const float* inputs = (const float*)d_in[0];
    const float* prev   = (const float*)d_in[1];
    const float* Wa     = (const float*)d_in[2];
    const float* Ua     = (const float*)d_in[3];
    const float* Va     = (const float*)d_in[4];
    const float* Ba     = (const float*)d_in[5];
    float* out = (float*)d_out;

    char* ws = (char*)d_ws;
    _Float16* B16   = (_Float16*)(ws);               // 2 MB packed Ua [dead after fused]
    float* wasPart  = (float*)(ws + (2u << 20));     // 4 MB [dead after was_reduce]
    float* wsWaS    = (float*)(ws + (6u << 20));     // 256 KB
    float* scores   = (float*)(ws + (6u << 20) + (256u << 10));  // 128 KB
    float* sm       = (float*)(ws + (6u << 20) + (384u << 10));  // 128 KB
    float* ctxPart  = (float*)(ws);                  // 4 MB, overlays dead B16+wasPart

    hipLaunchKernelGGL(k_pack_ua,    dim3(512),    dim3(256), 0, stream, Ua, B16);
    hipLaunchKernelGGL(k_was_part,   dim3(16, 64), dim3(256), 0, stream, prev, Wa, wasPart);
    hipLaunchKernelGGL(k_was_reduce, dim3(64),     dim3(256), 0, stream, wasPart, Ba, wsWaS);
    hipLaunchKernelGGL(k_fused_gemm, dim3(512),    dim3(512), 0, stream, inputs, B16, wsWaS, Va, scores);
    hipLaunchKernelGGL(k_softmax,    dim3(64),     dim3(256), 0, stream, scores, sm);
    hipLaunchKernelGGL(k_ctx_part,   dim3(16, 64), dim3(256), 0, stream, inputs, sm, ctxPart);
    hipLaunchKernelGGL(k_ctx_reduce, dim3(64),     dim3(256), 0, stream, ctxPart, out);
}

// Round 3
// 337.776 us; speedup vs baseline: 1.0158x; 1.0158x over previous
//
#include <hip/hip_runtime.h>

// CascadedAttentionCell: B=64, T=512, D=1024, OUT=1024 (all fp32 in/out)
//   WaS = prev@Wa + Ba;  UaH = inputs@Ua (68.7 GFLOP, fp16 MFMA);
//   scores = relu(tanh(UaH+WaS+Ba)@Va); sm = softmax_T; out = sum_t inputs*sm
// R5: B-latency attack. R2 post-mortem: 124 VGPR + 128 AGPR = 252/256 regs ->
// zero headroom -> compiler could not pipeline the 4 L2 B-loads per k-step ->
// util 64cyc/(64+300) = 18% == measured 18.6%. R3 post-mortem: launch_bounds
// (512,4) forced 128-reg cap -> 59.5 MB scratch spill (WRITE_SIZE), regression.
// Fix: 64x64 wave tile (acc[2][2]=64) at launch_bounds(512,2) => ~90 spare regs,
// spent on an EXPLICIT 4-deep B-fragment ring (32 VGPR, slot=ks8&3 static) +
// raw s_barrier with lgkmcnt(0)-only (no vmcnt drain) so B/A loads stay in
// flight across the per-chunk barrier (m201 counted-vmcnt pattern).

#define NBATCH 64
#define NT     512
#define NDIM   1024
#define NOUT   1024

typedef _Float16 h8 __attribute__((ext_vector_type(8)));
typedef _Float16 h4 __attribute__((ext_vector_type(4)));
typedef float f16v __attribute__((ext_vector_type(16)));

__device__ __forceinline__ float tanh_fast(float x) {
    float e = __expf(2.0f * x);
    return 1.0f - 2.0f * __builtin_amdgcn_rcpf(e + 1.0f);
}

// ---- K2a: pack Ua (fp32 [K=1024][N=1024]) into fp16 B-fragment order ----
// t = ((nt*64+ks)*64) + kg*32 + nn ; thread writes 8 contiguous fp16 (16 B).
__global__ __launch_bounds__(256) void k_pack_ua(const float* __restrict__ Ua,
                                                 _Float16* __restrict__ B16) {
    int t = blockIdx.x * 256 + threadIdx.x;   // 0..131071
    int nn = t & 31, kg = (t >> 5) & 1, ks = (t >> 6) & 63, nt = t >> 12;
    int n = (nt << 5) + nn;
    int kbase = (ks << 4) + (kg << 3);
    h8 v;
#pragma unroll
    for (int j = 0; j < 8; ++j) v[j] = (_Float16)Ua[(size_t)(kbase + j) * 1024 + n];
    *(h8*)(B16 + ((size_t)t << 3)) = v;
}

// ---- K1: WaS partials: part[oc][b][p] = sum_{o in chunk} ps[b][o]*Wa[o][p] ----
__global__ __launch_bounds__(256) void k_was_part(const float* __restrict__ ps,
                                                  const float* __restrict__ Wa,
                                                  float* __restrict__ part) {
    int oc = blockIdx.x, b = blockIdx.y, tid = threadIdx.x;
    const float4* Wa4 = (const float4*)Wa;
    const float* psb = ps + b * 1024;
    float4 acc = {0.f, 0.f, 0.f, 0.f};
    int o0 = oc * 64;
#pragma unroll 4
    for (int o = o0; o < o0 + 64; ++o) {
        float s = psb[o];
        float4 wv = Wa4[o * 256 + tid];
        acc.x += s * wv.x; acc.y += s * wv.y; acc.z += s * wv.z; acc.w += s * wv.w;
    }
    ((float4*)part)[((oc << 6) + b) * 256 + tid] = acc;
}

// ---- K1b: wsWaS[b][p] = Ba[p] + sum_oc part ----
__global__ __launch_bounds__(256) void k_was_reduce(const float* __restrict__ part,
                                                    const float* __restrict__ Ba,
                                                    float* __restrict__ wsWaS) {
    int b = blockIdx.x, tid = threadIdx.x;
    const float4* p4 = (const float4*)part;
    float4 acc = ((const float4*)Ba)[tid];
#pragma unroll
    for (int oc = 0; oc < 16; ++oc) {
        float4 v = p4[((oc << 6) + b) * 256 + tid];
        acc.x += v.x; acc.y += v.y; acc.z += v.z; acc.w += v.w;
    }
    ((float4*)wsWaS)[b * 256 + tid] = acc;
}

// ---- K3: fused  scores[r] = relu( sum_n tanh(UaH[r][n]+wsWaS[b][n]) * Va[n] ) ----
// 512 threads = 8 waves; wave wv owns cols [pass*512 + wv*64, +64) (acc[2][2]).
// 64-row strip per block (grid 512); A chunk (64x128 fp32) double-buffered in LDS
// with register prefetch; B fragments software-pipelined 4 k-steps deep from L2.
#define ASH_STRIDE 136   // fp16 units; 272 B rows: 16B-aligned, ~2 extra cyc/b128
__global__ __launch_bounds__(512, 2) void k_fused_gemm(
    const float* __restrict__ inputs, const _Float16* __restrict__ B16,
    const float* __restrict__ wsWaS, const float* __restrict__ Va,
    float* __restrict__ scores)
{
    __shared__ _Float16 Ash[2][64 * ASH_STRIDE];
    __shared__ float scoreSh[64];
    const int tid = threadIdx.x;                 // 0..511
    const int lane = tid & 63, wv = tid >> 6;    // wv = col group 0..7
    const int l31 = lane & 31, lhi = lane >> 5;
    const int r0 = blockIdx.x * 64;
    const int b = r0 >> 9;
    const int srow = tid >> 3, sq = tid & 7;     // 8 threads/row, 16 floats each
    const float4* srcBase = (const float4*)inputs + (size_t)(r0 + srow) * 256 + sq * 4;

    if (tid < 64) scoreSh[tid] = 0.0f;

    float4 vA[4];
#pragma unroll
    for (int j = 0; j < 4; ++j) vA[j] = srcBase[j];          // chunk 0
    {
        _Float16* dst = &Ash[0][srow * ASH_STRIDE + sq * 16];
#pragma unroll
        for (int j = 0; j < 4; ++j) {
            float4 v = vA[j];
            *(h4*)(dst + j * 4) =
                (h4){ (_Float16)v.x, (_Float16)v.y, (_Float16)v.z, (_Float16)v.w };
        }
    }
    __syncthreads();

    for (int pass = 0; pass < 2; ++pass) {
        const int c0w = pass * 512 + wv * 64;
        const int ntb = c0w >> 5;
        // B frag addr for (ct, ks): bBase + ct*2^15 + ks*2^9   (fp16 units)
        const _Float16* bBase = B16 + ((size_t)ntb << 15) + lane * 8;
        f16v acc[2][2];
#pragma unroll
        for (int rt = 0; rt < 2; ++rt)
#pragma unroll
            for (int ct = 0; ct < 2; ++ct)
#pragma unroll
                for (int e = 0; e < 16; ++e) acc[rt][ct][e] = 0.0f;

        // B ring pipeline: 4 k-steps deep (slot = ks8 & 3, static after unroll)
        h8 bp[4][2];
#pragma unroll
        for (int s = 0; s < 4; ++s) {
            bp[s][0] = *(const h8*)(bBase + ((size_t)s << 9));
            bp[s][1] = *(const h8*)(bBase + (1u << 15) + ((size_t)s << 9));
        }

        for (int kc = 0; kc < 8; ++kc) {
            const int buf = kc & 1;
            const bool pf = !(pass == 1 && kc == 7);
            if (pf) {   // issue next chunk's HBM loads before the MFMAs
                const float4* src = srcBase + (((kc + 1) & 7) << 5);
#pragma unroll
                for (int j = 0; j < 4; ++j) vA[j] = src[j];
            }
#pragma unroll
            for (int ks8 = 0; ks8 < 8; ++ks8) {
                const int ks = kc * 8 + ks8;
                const int slot = ks8 & 3;
                h8 a0 = *(const h8*)&Ash[buf][l31 * ASH_STRIDE + ks8 * 16 + lhi * 8];
                h8 a1 = *(const h8*)&Ash[buf][(32 + l31) * ASH_STRIDE + ks8 * 16 + lhi * 8];
                acc[0][0] = __builtin_amdgcn_mfma_f32_32x32x16_f16(a0, bp[slot][0], acc[0][0], 0, 0, 0);
                acc[1][0] = __builtin_amdgcn_mfma_f32_32x32x16_f16(a1, bp[slot][0], acc[1][0], 0, 0, 0);
                acc[0][1] = __builtin_amdgcn_mfma_f32_32x32x16_f16(a0, bp[slot][1], acc[0][1], 0, 0, 0);
                acc[1][1] = __builtin_amdgcn_mfma_f32_32x32x16_f16(a1, bp[slot][1], acc[1][1], 0, 0, 0);
                if (ks + 4 < 64) {   // reissue this slot for k-step ks+4
                    bp[slot][0] = *(const h8*)(bBase + ((size_t)(ks + 4) << 9));
                    bp[slot][1] = *(const h8*)(bBase + (1u << 15) + ((size_t)(ks + 4) << 9));
                }
            }
            if (pf) {   // vA loads have drained during MFMAs; convert + stage
                _Float16* dst = &Ash[buf ^ 1][srow * ASH_STRIDE + sq * 16];
#pragma unroll
                for (int j = 0; j < 4; ++j) {
                    float4 v = vA[j];
                    *(h4*)(dst + j * 4) =
                        (h4){ (_Float16)v.x, (_Float16)v.y, (_Float16)v.z, (_Float16)v.w };
                }
            }
            // raw barrier: drain LDS ops only — keep global loads in flight
            asm volatile("s_waitcnt lgkmcnt(0)" ::: "memory");
            __builtin_amdgcn_s_barrier();
        }
        // epilogue: tanh + Va dot, reduce over this wave's 64 cols
        float wsv[2], vav[2];
#pragma unroll
        for (int ct = 0; ct < 2; ++ct) {
            int n = c0w + ct * 32 + l31;
            wsv[ct] = wsWaS[b * 1024 + n];
            vav[ct] = Va[n];
        }
#pragma unroll
        for (int rt = 0; rt < 2; ++rt) {
#pragma unroll
            for (int i = 0; i < 16; ++i) {
                float s = 0.0f;
#pragma unroll
                for (int ct = 0; ct < 2; ++ct)
                    s += tanh_fast(acc[rt][ct][i] + wsv[ct]) * vav[ct];
                s += __shfl_xor(s, 1);
                s += __shfl_xor(s, 2);
                s += __shfl_xor(s, 4);
                s += __shfl_xor(s, 8);
                s += __shfl_xor(s, 16);
                if (l31 == 0) {
                    int row = rt * 32 + (i & 3) + ((i >> 2) << 3) + (lhi << 2);
                    atomicAdd(&scoreSh[row], s);
                }
            }
        }
    }
    __syncthreads();
    if (tid < 64) scores[r0 + tid] = fmaxf(scoreSh[tid], 0.0f);
}

// ---- K4: softmax over T=512 per batch ----
__global__ __launch_bounds__(256) void k_softmax(const float* __restrict__ scores,
                                                 float* __restrict__ sm) {
    int b = blockIdx.x, tid = threadIdx.x;
    __shared__ float red[256];
    const float* sb = scores + b * 512;
    float s0 = sb[tid], s1 = sb[tid + 256];
    red[tid] = fmaxf(s0, s1);
    __syncthreads();
    for (int st = 128; st > 0; st >>= 1) {
        if (tid < st) red[tid] = fmaxf(red[tid], red[tid + st]);
        __syncthreads();
    }
    float m = red[0];
    __syncthreads();
    float e0 = __expf(s0 - m), e1 = __expf(s1 - m);
    red[tid] = e0 + e1;
    __syncthreads();
    for (int st = 128; st > 0; st >>= 1) {
        if (tid < st) red[tid] += red[tid + st];
        __syncthreads();
    }
    float inv = 1.0f / red[0];
    sm[b * 512 + tid] = e0 * inv;
    sm[b * 512 + 256 + tid] = e1 * inv;
}

// ---- K5: context partials over 32-timestep slices (16 slices -> 1024 blocks) ----
__global__ __launch_bounds__(256) void k_ctx_part(const float* __restrict__ inputs,
                                                  const float* __restrict__ sm,
                                                  float* __restrict__ part) {
    int ts = blockIdx.x, b = blockIdx.y, tid = threadIdx.x;
    const float4* inF4 = (const float4*)inputs;
    float4 acc = {0.f, 0.f, 0.f, 0.f};
    int t0 = ts * 32;
#pragma unroll 8
    for (int t = t0; t < t0 + 32; ++t) {
        float wgt = sm[b * 512 + t];
        float4 x = inF4[(size_t)(b * 512 + t) * 256 + tid];
        acc.x += wgt * x.x; acc.y += wgt * x.y; acc.z += wgt * x.z; acc.w += wgt * x.w;
    }
    ((float4*)part)[((ts << 6) + b) * 256 + tid] = acc;
}

// ---- K6: reduce 16 slices -> d_out ----
__global__ __launch_bounds__(256) void k_ctx_reduce(const float* __restrict__ part,
                                                    float* __restrict__ out) {
    int g = blockIdx.x * 256 + threadIdx.x;
    const float4* p4 = (const float4*)part;
    float4 acc = p4[g];
#pragma unroll
    for (int s = 1; s < 16; ++s) {
        float4 v = p4[s * 16384 + g];
        acc.x += v.x; acc.y += v.y; acc.z += v.z; acc.w += v.w;
    }
    ((float4*)out)[g] = acc;
}

extern "C" void kernel_launch(void* const* d_in, const int* in_sizes, int n_in,
                              void* d_out, int out_size, void* d_ws, size_t ws_size,
                              hipStream_t stream) {
    const float* inputs = (const float*)d_in[0];
    const float* prev   = (const float*)d_in[1];
    const float* Wa     = (const float*)d_in[2];
    const float* Ua     = (const float*)d_in[3];
    const float* Va     = (const float*)d_in[4];
    const float* Ba     = (const float*)d_in[5];
    float* out = (float*)d_out;

    char* ws = (char*)d_ws;
    _Float16* B16   = (_Float16*)(ws);               // 2 MB packed Ua [dead after fused]
    float* wasPart  = (float*)(ws + (2u << 20));     // 4 MB [dead after was_reduce]
    float* wsWaS    = (float*)(ws + (6u << 20));     // 256 KB
    float* scores   = (float*)(ws + (6u << 20) + (256u << 10));  // 128 KB
    float* sm       = (float*)(ws + (6u << 20) + (384u << 10));  // 128 KB
    float* ctxPart  = (float*)(ws);                  // 4 MB, overlays dead B16+wasPart

    hipLaunchKernelGGL(k_pack_ua,    dim3(512),    dim3(256), 0, stream, Ua, B16);
    hipLaunchKernelGGL(k_was_part,   dim3(16, 64), dim3(256), 0, stream, prev, Wa, wasPart);
    hipLaunchKernelGGL(k_was_reduce, dim3(64),     dim3(256), 0, stream, wasPart, Ba, wsWaS);
    hipLaunchKernelGGL(k_fused_gemm, dim3(512),    dim3(512), 0, stream, inputs, B16, wsWaS, Va, scores);
    hipLaunchKernelGGL(k_softmax,    dim3(64),     dim3(256), 0, stream, scores, sm);
    hipLaunchKernelGGL(k_ctx_part,   dim3(16, 64), dim3(256), 0, stream, inputs, sm, ctxPart);
    hipLaunchKernelGGL(k_ctx_reduce, dim3(64),     dim3(256), 0, stream, ctxPart, out);
}

// Round 5
// 330.328 us; speedup vs baseline: 1.0387x; 1.0225x over previous
//
#include <hip/hip_runtime.h>

// CascadedAttentionCell: B=64, T=512, D=1024, OUT=1024 (all fp32 in/out)
//   WaS = prev@Wa + Ba;  UaH = inputs@Ua (68.7 GFLOP, fp16 MFMA);
//   scores = relu(tanh(UaH+WaS+Ba)@Va); sm = softmax_T; out = sum_t inputs*sm
// R7: near-barrier-free K-loop, corrected swizzle. R6 had a swizzle-fold bug
// ((16lhi^swz)+32ks != (32ks+16lhi)^swz: swz bits 4-6 collide with 32ks) and
// 128.25 KiB static LDS (possible launch-cap abort). Now: A staged in TWO
// 64 KiB fp16 halves (K=512 each) -> 3 barriers total, 32 barrier-free k-steps
// per half; per-slot swizzled offsets aoff[s]=(32s+16lhi)^((row&7)<<4) are
// exact (XOR window < 128B, k-loop strides 128B). Single pass: wave owns 128
// cols (acc[2][4]=128 AGPR) + explicit 4-deep B ring (bp[4][4]=64 VGPR),
// ~230/256 unified regs. B-ring runs seamlessly across the half boundary.

#define NBATCH 64
#define NT     512
#define NDIM   1024
#define NOUT   1024

typedef _Float16 h8 __attribute__((ext_vector_type(8)));
typedef _Float16 h4 __attribute__((ext_vector_type(4)));
typedef float f16v __attribute__((ext_vector_type(16)));

__device__ __forceinline__ float tanh_fast(float x) {
    float e = __expf(2.0f * x);
    return 1.0f - 2.0f * __builtin_amdgcn_rcpf(e + 1.0f);
}

// ---- K2a: pack Ua (fp32 [K=1024][N=1024]) into fp16 B-fragment order ----
// t = ((nt*64+ks)*64) + kg*32 + nn ; thread writes 8 contiguous fp16 (16 B).
__global__ __launch_bounds__(256) void k_pack_ua(const float* __restrict__ Ua,
                                                 _Float16* __restrict__ B16) {
    int t = blockIdx.x * 256 + threadIdx.x;   // 0..131071
    int nn = t & 31, kg = (t >> 5) & 1, ks = (t >> 6) & 63, nt = t >> 12;
    int n = (nt << 5) + nn;
    int kbase = (ks << 4) + (kg << 3);
    h8 v;
#pragma unroll
    for (int j = 0; j < 8; ++j) v[j] = (_Float16)Ua[(size_t)(kbase + j) * 1024 + n];
    *(h8*)(B16 + ((size_t)t << 3)) = v;
}

// ---- K1: WaS partials: part[oc][b][p] = sum_{o in chunk} ps[b][o]*Wa[o][p] ----
__global__ __launch_bounds__(256) void k_was_part(const float* __restrict__ ps,
                                                  const float* __restrict__ Wa,
                                                  float* __restrict__ part) {
    int oc = blockIdx.x, b = blockIdx.y, tid = threadIdx.x;
    const float4* Wa4 = (const float4*)Wa;
    const float* psb = ps + b * 1024;
    float4 acc = {0.f, 0.f, 0.f, 0.f};
    int o0 = oc * 64;
#pragma unroll 4
    for (int o = o0; o < o0 + 64; ++o) {
        float s = psb[o];
        float4 wv = Wa4[o * 256 + tid];
        acc.x += s * wv.x; acc.y += s * wv.y; acc.z += s * wv.z; acc.w += s * wv.w;
    }
    ((float4*)part)[((oc << 6) + b) * 256 + tid] = acc;
}

// ---- K1b: wsWaS[b][p] = Ba[p] + sum_oc part ----
__global__ __launch_bounds__(256) void k_was_reduce(const float* __restrict__ part,
                                                    const float* __restrict__ Ba,
                                                    float* __restrict__ wsWaS) {
    int b = blockIdx.x, tid = threadIdx.x;
    const float4* p4 = (const float4*)part;
    float4 acc = ((const float4*)Ba)[tid];
#pragma unroll
    for (int oc = 0; oc < 16; ++oc) {
        float4 v = p4[((oc << 6) + b) * 256 + tid];
        acc.x += v.x; acc.y += v.y; acc.z += v.z; acc.w += v.w;
    }
    ((float4*)wsWaS)[b * 256 + tid] = acc;
}

// ---- K3: fused  scores[r] = relu( sum_n tanh(UaH[r][n]+wsWaS[b][n]) * Va[n] ) ----
// 512 threads = 8 waves; wave wv owns cols [wv*128, wv*128+128) (acc[2][4]).
// A strip staged fp16 in two 64 KiB halves (K=512 each), XOR-swizzled rows;
// 32 barrier-free k-steps per half. B frags: 4-deep register ring from L2.
__global__ __launch_bounds__(512, 2) void k_fused_gemm(
    const float* __restrict__ inputs, const _Float16* __restrict__ B16,
    const float* __restrict__ wsWaS, const float* __restrict__ Va,
    float* __restrict__ scores)
{
    __shared__ _Float16 Ash[64 * 512];   // 64 KiB, rows 1024 B, XOR-swizzled
    __shared__ float scoreSh[64];
    const int tid = threadIdx.x;                 // 0..511
    const int lane = tid & 63, wv = tid >> 6;    // wv = col group 0..7
    const int l31 = lane & 31, lhi = lane >> 5;
    const int r0 = blockIdx.x * 64;
    const int b = r0 >> 9;
    const int srow = tid >> 3, sq = tid & 7;     // staging: 8 threads/row

    if (tid < 64) scoreSh[tid] = 0.0f;

    const int ntb = wv << 2;                     // 4 col-tiles of 32
    const _Float16* bBase = B16 + ((size_t)ntb << 15) + lane * 8;

    f16v acc[2][4];
#pragma unroll
    for (int rt = 0; rt < 2; ++rt)
#pragma unroll
        for (int ct = 0; ct < 4; ++ct)
#pragma unroll
            for (int e = 0; e < 16; ++e) acc[rt][ct][e] = 0.0f;

    // B ring: 4 k-steps deep; slot s always holds k-step ks with ks%4 == s.
    h8 bp[4][4];
#pragma unroll
    for (int s = 0; s < 4; ++s)
#pragma unroll
        for (int ct = 0; ct < 4; ++ct)
            bp[s][ct] = *(const h8*)(bBase + ((size_t)ct << 15) + ((size_t)s << 9));

    // A read offsets: logical byte L = 128*ks4 + 32*s + 16*lhi; physical =
    // 128*ks4 + ((32*s+16*lhi) ^ swz)  — exact since swz bits 4-6 < 128.
    const int aswz = (l31 & 7) << 4;
    int aoff[4];
#pragma unroll
    for (int s = 0; s < 4; ++s) aoff[s] = (32 * s + 16 * lhi) ^ aswz;
    const char* a0b = (const char*)Ash + l31 * 1024;
    const char* a1b = a0b + 32 * 1024;
    const int swz = (srow & 7) << 4;

#pragma unroll
    for (int h = 0; h < 2; ++h) {
        if (h == 1) __syncthreads();   // all waves done reading half 0
        {   // stage half h: fp32 HBM -> fp16 LDS, swizzled (HBM-roofline phase)
            const float4* src = (const float4*)inputs +
                                (size_t)(r0 + srow) * 256 + (h << 7) + sq;
            char* rowb = (char*)Ash + srow * 1024;
#pragma unroll 8
            for (int jj = 0; jj < 16; ++jj) {      // 8 threads/row = 128 B contig
                float4 v = src[jj * 8];
                *(h4*)(rowb + ((64 * jj + 8 * sq) ^ swz)) =
                    (h4){ (_Float16)v.x, (_Float16)v.y, (_Float16)v.z, (_Float16)v.w };
            }
        }
        __syncthreads();

        for (int ks4 = 0; ks4 < 8; ++ks4) {        // barrier-free K-half
#pragma unroll
            for (int s = 0; s < 4; ++s) {
                const int ks = (h << 5) + ks4 * 4 + s;
                h8 a0 = *(const h8*)(a0b + ks4 * 128 + aoff[s]);
                h8 a1 = *(const h8*)(a1b + ks4 * 128 + aoff[s]);
#pragma unroll
                for (int ct = 0; ct < 4; ++ct) {
                    acc[0][ct] = __builtin_amdgcn_mfma_f32_32x32x16_f16(a0, bp[s][ct], acc[0][ct], 0, 0, 0);
                    acc[1][ct] = __builtin_amdgcn_mfma_f32_32x32x16_f16(a1, bp[s][ct], acc[1][ct], 0, 0, 0);
                }
                if (h == 0 || ks4 < 7) {   // reissue slot for k-step ks+4 (<64)
#pragma unroll
                    for (int ct = 0; ct < 4; ++ct)
                        bp[s][ct] = *(const h8*)(bBase + ((size_t)ct << 15) +
                                                 ((size_t)(ks + 4) << 9));
                }
            }
        }
    }

    // epilogue: tanh + Va dot, reduce over this wave's 128 cols
    float wsv[4], vav[4];
#pragma unroll
    for (int ct = 0; ct < 4; ++ct) {
        int n = (wv << 7) + ct * 32 + l31;
        wsv[ct] = wsWaS[b * 1024 + n];
        vav[ct] = Va[n];
    }
#pragma unroll
    for (int rt = 0; rt < 2; ++rt) {
#pragma unroll
        for (int i = 0; i < 16; ++i) {
            float s = 0.0f;
#pragma unroll
            for (int ct = 0; ct < 4; ++ct)
                s += tanh_fast(acc[rt][ct][i] + wsv[ct]) * vav[ct];
            s += __shfl_xor(s, 1);
            s += __shfl_xor(s, 2);
            s += __shfl_xor(s, 4);
            s += __shfl_xor(s, 8);
            s += __shfl_xor(s, 16);
            if (l31 == 0) {
                int row = rt * 32 + (i & 3) + ((i >> 2) << 3) + (lhi << 2);
                atomicAdd(&scoreSh[row], s);
            }
        }
    }
    __syncthreads();
    if (tid < 64) scores[r0 + tid] = fmaxf(scoreSh[tid], 0.0f);
}

// ---- K4: softmax over T=512 per batch ----
__global__ __launch_bounds__(256) void k_softmax(const float* __restrict__ scores,
                                                 float* __restrict__ sm) {
    int b = blockIdx.x, tid = threadIdx.x;
    __shared__ float red[256];
    const float* sb = scores + b * 512;
    float s0 = sb[tid], s1 = sb[tid + 256];
    red[tid] = fmaxf(s0, s1);
    __syncthreads();
    for (int st = 128; st > 0; st >>= 1) {
        if (tid < st) red[tid] = fmaxf(red[tid], red[tid + st]);
        __syncthreads();
    }
    float m = red[0];
    __syncthreads();
    float e0 = __expf(s0 - m), e1 = __expf(s1 - m);
    red[tid] = e0 + e1;
    __syncthreads();
    for (int st = 128; st > 0; st >>= 1) {
        if (tid < st) red[tid] += red[tid + st];
        __syncthreads();
    }
    float inv = 1.0f / red[0];
    sm[b * 512 + tid] = e0 * inv;
    sm[b * 512 + 256 + tid] = e1 * inv;
}

// ---- K5: context partials over 32-timestep slices (16 slices -> 1024 blocks) ----
__global__ __launch_bounds__(256) void k_ctx_part(const float* __restrict__ inputs,
                                                  const float* __restrict__ sm,
                                                  float* __restrict__ part) {
    int ts = blockIdx.x, b = blockIdx.y, tid = threadIdx.x;
    const float4* inF4 = (const float4*)inputs;
    float4 acc = {0.f, 0.f, 0.f, 0.f};
    int t0 = ts * 32;
#pragma unroll 8
    for (int t = t0; t < t0 + 32; ++t) {
        float wgt = sm[b * 512 + t];
        float4 x = inF4[(size_t)(b * 512 + t) * 256 + tid];
        acc.x += wgt * x.x; acc.y += wgt * x.y; acc.z += wgt * x.z; acc.w += wgt * x.w;
    }
    ((float4*)part)[((ts << 6) + b) * 256 + tid] = acc;
}

// ---- K6: reduce 16 slices -> d_out ----
__global__ __launch_bounds__(256) void k_ctx_reduce(const float* __restrict__ part,
                                                    float* __restrict__ out) {
    int g = blockIdx.x * 256 + threadIdx.x;
    const float4* p4 = (const float4*)part;
    float4 acc = p4[g];
#pragma unroll
    for (int s = 1; s < 16; ++s) {
        float4 v = p4[s * 16384 + g];
        acc.x += v.x; acc.y += v.y; acc.z += v.z; acc.w += v.w;
    }
    ((float4*)out)[g] = acc;
}

extern "C" void kernel_launch(void* const* d_in, const int* in_sizes, int n_in,
                              void* d_out, int out_size, void* d_ws, size_t ws_size,
                              hipStream_t stream) {
    const float* inputs = (const float*)d_in[0];
    const float* prev   = (const float*)d_in[1];
    const float* Wa     = (const float*)d_in[2];
    const float* Ua     = (const float*)d_in[3];
    const float* Va     = (const float*)d_in[4];
    const float* Ba     = (const float*)d_in[5];
    float* out = (float*)d_out;

    char* ws = (char*)d_ws;
    _Float16* B16   = (_Float16*)(ws);               // 2 MB packed Ua [dead after fused]
    float* wasPart  = (float*)(ws + (2u << 20));     // 4 MB [dead after was_reduce]
    float* wsWaS    = (float*)(ws + (6u << 20));     // 256 KB
    float* scores   = (float*)(ws + (6u << 20) + (256u << 10));  // 128 KB
    float* sm       = (float*)(ws + (6u << 20) + (384u << 10));  // 128 KB
    float* ctxPart  = (float*)(ws);                  // 4 MB, overlays dead B16+wasPart

    hipLaunchKernelGGL(k_pack_ua,    dim3(512),    dim3(256), 0, stream, Ua, B16);
    hipLaunchKernelGGL(k_was_part,   dim3(16, 64), dim3(256), 0, stream, prev, Wa, wasPart);
    hipLaunchKernelGGL(k_was_reduce, dim3(64),     dim3(256), 0, stream, wasPart, Ba, wsWaS);
    hipLaunchKernelGGL(k_fused_gemm, dim3(512),    dim3(512), 0, stream, inputs, B16, wsWaS, Va, scores);
    hipLaunchKernelGGL(k_softmax,    dim3(64),     dim3(256), 0, stream, scores, sm);
    hipLaunchKernelGGL(k_ctx_part,   dim3(16, 64), dim3(256), 0, stream, inputs, sm, ctxPart);
    hipLaunchKernelGGL(k_ctx_reduce, dim3(64),     dim3(256), 0, stream, ctxPart, out);
}